// Round 7
// baseline (160.215 us; speedup 1.0000x reference)
//
#include <hip/hip_runtime.h>
#include <hip/hip_bf16.h>

#define D_MODEL 1024
#define NHEADS  16
#define HEADD   64
#define SEQ     2048
#define PERIOD  4096
#define LOG2E   1.44269504088896340736f

typedef __attribute__((ext_vector_type(4)))  float f32x4;
typedef __attribute__((ext_vector_type(16))) float f32x16;
typedef __attribute__((ext_vector_type(4)))  float fvec4;
typedef __attribute__((ext_vector_type(8)))  short s16x8;
typedef __attribute__((ext_vector_type(4)))  short s16x4;
typedef __attribute__((ext_vector_type(2)))  int   i32x2;
typedef __attribute__((ext_vector_type(4)))  int   i32x4;

__device__ __forceinline__ short bf16_bits(float f) {
    union { float f; unsigned u; } v; v.f = f;
    unsigned r = v.u + 0x7FFFu + ((v.u >> 16) & 1u);   // RNE
    return (short)(r >> 16);
}

__device__ __forceinline__ int cvt_pk_bf16(float a, float b) {
    int r;
    asm("v_cvt_pk_bf16_f32 %0, %1, %2" : "=v"(r) : "v"(a), "v"(b));
    return r;
}

__device__ __forceinline__ float exp2_hw(float x) {
    float r;
    asm("v_exp_f32 %0, %1" : "=v"(r) : "v"(x));   // bare 2^x, no OCML range code
    return r;
}

__device__ __forceinline__ void gload_lds16(const void* g, void* l) {
    __builtin_amdgcn_global_load_lds(
        (const __attribute__((address_space(1))) void*)g,
        (__attribute__((address_space(3))) void*)l, 16, 0, 0);
}

// ---------------- prep: x f32 -> bf16 ----------------
__global__ void cvt_x(const float* __restrict__ x, short* __restrict__ xb) {
    int i = blockIdx.x * blockDim.x + threadIdx.x;
    fvec4 v = ((const fvec4*)x)[i];
    s16x4 o;
    o.x = bf16_bits(v.x); o.y = bf16_bits(v.y);
    o.z = bf16_bits(v.z); o.w = bf16_bits(v.w);
    ((s16x4*)xb)[i] = o;
}

// ---------------- prep: W [K][N] f32 -> Wt [N][K] bf16 ----------------
__global__ void transpose_w(const float* __restrict__ src, short* __restrict__ dst) {
    __shared__ float tile[64][65];
    int bx = blockIdx.x & 15, by = blockIdx.x >> 4;
    int n0 = bx * 64, k0 = by * 64;
    int t = threadIdx.x;
    int cr = t >> 4;
    int cc = (t & 15) * 4;
    for (int i = 0; i < 4; ++i) {
        int row = cr + i * 16;
        fvec4 v = *(const fvec4*)&src[(k0 + row) * D_MODEL + n0 + cc];
        tile[row][cc+0] = v.x; tile[row][cc+1] = v.y;
        tile[row][cc+2] = v.z; tile[row][cc+3] = v.w;
    }
    __syncthreads();
    for (int i = 0; i < 4; ++i) {
        int row = cr + i * 16;
        s16x4 o;
        o.x = bf16_bits(tile[cc+0][row]);
        o.y = bf16_bits(tile[cc+1][row]);
        o.z = bf16_bits(tile[cc+2][row]);
        o.w = bf16_bits(tile[cc+3][row]);
        *(s16x4*)&dst[(n0 + row) * D_MODEL + k0 + cc] = o;
    }
}

// ---------------- V [4096][1024] bf16 -> vt[(b*1024+h*64+d)][s] ----------------
__global__ void transpose_v(const short* __restrict__ vb, short* __restrict__ vt) {
    __shared__ short tile[64][80];
    int bh = blockIdx.y, st = blockIdx.x;
    int b = bh >> 4, h = bh & 15;
    int s0 = st * 64;
    int t = threadIdx.x;
    int row = t >> 3, ch = t & 7;
    for (int i = 0; i < 2; ++i) {
        int r = row + i * 32;
        *(s16x8*)&tile[r][ch * 8] =
            *(const s16x8*)&vb[(b * SEQ + s0 + r) * D_MODEL + h * HEADD + ch * 8];
    }
    __syncthreads();
    for (int i = 0; i < 2; ++i) {
        int d = row + i * 32;
        s16x8 o;
        #pragma unroll
        for (int j = 0; j < 8; ++j) o[j] = tile[ch * 8 + j][d];
        *(s16x8*)&vt[(b * D_MODEL + h * HEADD + d) * SEQ + s0 + ch * 8] = o;
    }
}

// ---------------- prep: phase-replicated bias table (log2 domain, minus fixed max) ----------------
// biasq[h*4096 + a] = {b[a..a+3]} * LOG2E - 16   (fixed-max softmax: m=16 folded in)
__global__ void build_biasq(const float* __restrict__ rb, f32x4* __restrict__ bq4) {
    int id = blockIdx.x * 256 + threadIdx.x;   // 0..65535 = h*4096 + a
    int h = id >> 12, a = id & 4095;
    f32x4 v;
    #pragma unroll
    for (int j = 0; j < 4; ++j)
        v[j] = rb[((a + j) & (PERIOD - 1)) * NHEADS + h] * LOG2E - 16.0f;
    bq4[id] = v;
}

// ---------------- GEMM: C = A[M,1024]b @ Bt[n][k]b + bias ----------------
// 128x64 tile, BK=64, dbuf global_load_lds with counted-wait raw-barrier pipeline.
// MODE 0: Q (scale 0.125*log2e, bf16 out)   1: bf16 out    3: f32 out
template<int MODE>
__global__ __launch_bounds__(256) void gemm_bias(
    const short* __restrict__ A, const short* __restrict__ Bt,
    const float* __restrict__ bias, void* __restrict__ Cout)
{
    __shared__ short As[2][128 * 64];   // 2 x 16 KB
    __shared__ short Bs[2][64 * 64];    // 2 x  8 KB
    int tid = threadIdx.x;
    int lane = tid & 63, wid = tid >> 6;
    int ln = lane & 15, g = lane >> 4;
    int wr = (wid >> 1) * 64, wc = (wid & 1) * 32;

    // XCD swizzle: same-M-panel blocks grouped per XCD (A panel L2-resident)
    int bid = blockIdx.x;                 // 0..511
    int xcd = bid & 7, slot = bid >> 3;   // slot 0..63
    int mb = xcd * 4 + (slot >> 4);       // 0..31
    int nb = slot & 15;                   // 0..15
    int m0 = mb * 128, n0 = nb * 64;

    f32x4 acc[4][2] = {};

    auto STAGE = [&](int kt, int bi) {
        #pragma unroll
        for (int i = 0; i < 4; ++i) {           // A: 128 rows x 8 chunks
            int idx = i * 256 + tid;
            int row = idx >> 3, ch = idx & 7;
            int gch = ch ^ (row & 7);
            gload_lds16(&A[(m0 + row) * 1024 + kt + gch * 8],
                        (char*)&As[bi][0] + (i * 256 + wid * 64) * 16);
        }
        #pragma unroll
        for (int i = 0; i < 2; ++i) {           // B: 64 rows x 8 chunks
            int idx = i * 256 + tid;
            int row = idx >> 3, ch = idx & 7;
            int gch = ch ^ (row & 7);
            gload_lds16(&Bt[(n0 + row) * 1024 + kt + gch * 8],
                        (char*)&Bs[bi][0] + (i * 256 + wid * 64) * 16);
        }
    };

    STAGE(0, 0);

    for (int kt = 0; kt < 16; ++kt) {
        int bi = kt & 1;
        // stage(kt) was issued a full compute-phase ago -> this wait is ~free;
        // raw barrier does NOT drain the upcoming stage(kt+1).
        asm volatile("s_waitcnt vmcnt(0)" ::: "memory");
        __builtin_amdgcn_s_barrier();
        if (kt < 15) STAGE((kt + 1) * 64, bi ^ 1);   // stays in flight across next barrier

        s16x8 af[4][2], bfr[2][2];
        #pragma unroll
        for (int m = 0; m < 4; ++m) {
            int row = wr + m * 16 + ln;
            #pragma unroll
            for (int kc = 0; kc < 2; ++kc)
                af[m][kc] = *(const s16x8*)&As[bi][row * 64 + (((kc * 4 + g) ^ (row & 7)) * 8)];
        }
        #pragma unroll
        for (int n = 0; n < 2; ++n) {
            int row = wc + n * 16 + ln;
            #pragma unroll
            for (int kc = 0; kc < 2; ++kc)
                bfr[n][kc] = *(const s16x8*)&Bs[bi][row * 64 + (((kc * 4 + g) ^ (row & 7)) * 8)];
        }
        #pragma unroll
        for (int kc = 0; kc < 2; ++kc)
            #pragma unroll
            for (int m = 0; m < 4; ++m)
                #pragma unroll
                for (int n = 0; n < 2; ++n)
                    acc[m][n] = __builtin_amdgcn_mfma_f32_16x16x32_bf16(af[m][kc], bfr[n][kc], acc[m][n], 0, 0, 0);
    }

    #pragma unroll
    for (int m = 0; m < 4; ++m) {
        int gr0 = m0 + wr + m * 16 + g * 4;
        #pragma unroll
        for (int n = 0; n < 2; ++n) {
            int gc = n0 + wc + n * 16 + ln;
            float bv = bias[gc];
            #pragma unroll
            for (int r = 0; r < 4; ++r) {
                int gr = gr0 + r;
                float v = acc[m][n][r] + bv;
                if (MODE == 0)      ((short*)Cout)[gr * 1024 + gc] = bf16_bits(v * (0.125f * LOG2E));
                else if (MODE == 1) ((short*)Cout)[gr * 1024 + gc] = bf16_bits(v);
                else                ((float*)Cout)[gr * 1024 + gc] = v;
            }
        }
    }
}

// ---------------- fused flash attention: split-KV, fixed-max softmax, counted-wait pipeline ----------------
__global__ __launch_bounds__(512, 2) void attn_kernel(
    const short* __restrict__ qb,     // [4096][1024], pre-scaled by 0.125*log2e
    const short* __restrict__ kb,     // [4096][1024]
    const short* __restrict__ vt,     // [(b*1024+h*64+d)][2048]
    const f32x4* __restrict__ biasq,  // [16][4096], log2 domain, minus 16
    short* __restrict__ ao)           // [4096][1024]
{
    // [half][buf][0=K,1=V][64*64] shorts = 64 KB; merge area reuses this after the loop
    __shared__ short KV[2][2][2][64 * 64];

    int tid = threadIdx.x;
    int half = tid >> 8;               // 0: keys [0,1024)   1: keys [1024,2048)
    int tid_h = tid & 255;
    int lane = tid & 63;
    int wid_h = (tid >> 6) & 3;
    int l31 = lane & 31, hi = lane >> 5;

    // XCD swizzle: all 16 q-blocks of one (h,b) pinned to one XCD
    int bid = blockIdx.x;                 // 0..511
    int xcd = bid & 7, slot = bid >> 3;   // 0..63
    int hb = xcd * 4 + (slot >> 4);       // 0..31
    int qt = slot & 15;
    int h = hb & 15, b = hb >> 4;
    int q0 = qt * 128 + wid_h * 32;
    int qrow = q0 + l31;
    int kbase = half * 1024;

    // Q fragments (B-operand: col=q, k-contiguous)
    s16x8 aq[4];
    #pragma unroll
    for (int kk = 0; kk < 4; ++kk)
        aq[kk] = *(const s16x8*)&qb[(b * SEQ + qrow) * D_MODEL + h * HEADD + kk * 16 + hi * 8];

    const f32x4* bq = biasq + h * PERIOD;

    float lrow = 0.f;
    f32x16 ot[2] = {};

    auto STAGE = [&](int k0, int bi) {   // k0 absolute key index
        #pragma unroll
        for (int i = 0; i < 2; ++i) {
            int idx = i * 256 + tid_h;
            int row = idx >> 3, ch = idx & 7;
            int gch = ch ^ ((row & 7) ^ ((row >> 3) & 3));
            gload_lds16(&kb[(b * SEQ + k0 + row) * D_MODEL + h * HEADD + gch * 8],
                        (char*)&KV[half][bi][0][0] + (i * 256 + wid_h * 64) * 16);
            gload_lds16(&vt[(b * D_MODEL + h * HEADD + row) * SEQ + k0 + gch * 8],
                        (char*)&KV[half][bi][1][0] + (i * 256 + wid_h * 64) * 16);
        }
    };

    STAGE(kbase, 0);

    for (int kt = 0; kt < 16; ++kt) {
        int k0 = kbase + kt * 64;
        int bi = kt & 1;

        // stage(kt) issued a full compute-phase ago -> wait is ~free;
        // raw barrier keeps stage(kt+1) (issued below) in flight.
        asm volatile("s_waitcnt vmcnt(0)" ::: "memory");
        __builtin_amdgcn_s_barrier();

        // bias gathers FIRST (so the compiler's wait for them leaves stage(kt+1) in flight)
        f32x4 bv[2][4];
        #pragma unroll
        for (int kt32 = 0; kt32 < 2; ++kt32)
            #pragma unroll
            for (int rq = 0; rq < 4; ++rq) {
                int kq = k0 + kt32 * 32 + rq * 8 + hi * 4;
                bv[kt32][rq] = bq[(qrow - kq - 3) & (PERIOD - 1)];
            }
        __builtin_amdgcn_sched_barrier(0);   // pin: bias loads above, stage below
        if (kt < 15) STAGE(k0 + 64, bi ^ 1);
        __builtin_amdgcn_sched_barrier(0);   // keep stage issue early

        // S^T = K · Q^T  (rows=k, cols=q), log2 domain
        f32x16 s[2];
        const short* Ksp = &KV[half][bi][0][0];
        const short* Vsp = &KV[half][bi][1][0];
        __builtin_amdgcn_s_setprio(1);
        #pragma unroll
        for (int kt32 = 0; kt32 < 2; ++kt32) {
            f32x16 acc = {};
            int rowK = kt32 * 32 + l31;
            int swz = (rowK & 7) ^ ((rowK >> 3) & 3);
            #pragma unroll
            for (int kk = 0; kk < 4; ++kk) {
                s16x8 kf = *(const s16x8*)&Ksp[rowK * 64 + (((2 * kk + hi) ^ swz) * 8)];
                acc = __builtin_amdgcn_mfma_f32_32x32x16_bf16(kf, aq[kk], acc, 0, 0, 0);
            }
            s[kt32] = acc;
        }
        __builtin_amdgcn_s_setprio(0);

        // p = exp2(score + bias - 16): fixed-max softmax, bare v_exp_f32
        #pragma unroll
        for (int kt32 = 0; kt32 < 2; ++kt32)
            #pragma unroll
            for (int rq = 0; rq < 4; ++rq) {
                s[kt32][rq * 4 + 0] = exp2_hw(s[kt32][rq * 4 + 0] + bv[kt32][rq][3]);
                s[kt32][rq * 4 + 1] = exp2_hw(s[kt32][rq * 4 + 1] + bv[kt32][rq][2]);
                s[kt32][rq * 4 + 2] = exp2_hw(s[kt32][rq * 4 + 2] + bv[kt32][rq][1]);
                s[kt32][rq * 4 + 3] = exp2_hw(s[kt32][rq * 4 + 3] + bv[kt32][rq][0]);
            }

        // l accumulation: tree over 32 in-lane values + cross-half partner add
        float sm[16];
        #pragma unroll
        for (int t = 0; t < 16; ++t) sm[t] = s[0][t] + s[1][t];
        #pragma unroll
        for (int t = 0; t < 8; ++t) sm[t] += sm[t + 8];
        #pragma unroll
        for (int t = 0; t < 4; ++t) sm[t] += sm[t + 4];
        float psum = (sm[0] + sm[1]) + (sm[2] + sm[3]);
        {
            i32x2 r = __builtin_amdgcn_permlane32_swap(__float_as_int(psum), __float_as_int(psum), false, false);
            psum = __int_as_float(r[0]) + __int_as_float(r[1]);
        }
        lrow += psum;

        // P repack (regs only, proven shfl_xor form) + PV: O^T += V^T . P
        #pragma unroll
        for (int kt32 = 0; kt32 < 2; ++kt32) {
            int pk[8];
            #pragma unroll
            for (int i = 0; i < 8; ++i)
                pk[i] = cvt_pk_bf16(s[kt32][2 * i], s[kt32][2 * i + 1]);
            #pragma unroll
            for (int ks = 0; ks < 2; ++ks) {
                int a0 = pk[ks * 4 + 0], b0 = pk[ks * 4 + 2];
                int a1 = pk[ks * 4 + 1], b1 = pk[ks * 4 + 3];
                int a0s = __shfl_xor(a0, 32), b0s = __shfl_xor(b0, 32);
                int a1s = __shfl_xor(a1, 32), b1s = __shfl_xor(b1, 32);
                i32x4 wi;
                wi[0] = (lane < 32) ? a0 : b0s;   // k = hi*8 + 0,1
                wi[1] = (lane < 32) ? a1 : b1s;   // k = hi*8 + 2,3
                wi[2] = (lane < 32) ? a0s : b0;   // k = hi*8 + 4,5
                wi[3] = (lane < 32) ? a1s : b1;   // k = hi*8 + 6,7
                s16x8 pb = __builtin_bit_cast(s16x8, wi);
                __builtin_amdgcn_s_setprio(1);
                #pragma unroll
                for (int dd = 0; dd < 2; ++dd) {
                    int rowV = dd * 32 + l31;
                    int swzV = (rowV & 7) ^ ((rowV >> 3) & 3);
                    int chV = kt32 * 4 + ks * 2 + hi;
                    s16x8 vf = *(const s16x8*)&Vsp[rowV * 64 + ((chV ^ swzV) * 8)];
                    ot[dd] = __builtin_amdgcn_mfma_f32_32x32x16_bf16(vf, pb, ot[dd], 0, 0, 0);
                }
                __builtin_amdgcn_s_setprio(0);
            }
        }
    }

    __syncthreads();   // all waves done with K/V LDS before merge reuses it

    // ---- merge the two KV halves via LDS (K/V buffers are dead now) ----
    float* mbuf = (float*)&KV[0][0][0][0];
    float* slot_p = mbuf + (wid_h * 64 + lane) * 33;   // stride 33 -> conflict-free
    if (half == 1) {
        #pragma unroll
        for (int dd = 0; dd < 2; ++dd)
            #pragma unroll
            for (int t = 0; t < 16; ++t)
                slot_p[dd * 16 + t] = ot[dd][t];
        slot_p[32] = lrow;
    }
    __syncthreads();
    if (half == 0) {
        lrow += slot_p[32];
        float inv = 1.0f / lrow;
        int obase = (b * SEQ + qrow) * D_MODEL + h * HEADD;
        #pragma unroll
        for (int dd = 0; dd < 2; ++dd)
            #pragma unroll
            for (int rq = 0; rq < 4; ++rq) {
                float v0 = (ot[dd][rq * 4 + 0] + slot_p[dd * 16 + rq * 4 + 0]) * inv;
                float v1 = (ot[dd][rq * 4 + 1] + slot_p[dd * 16 + rq * 4 + 1]) * inv;
                float v2 = (ot[dd][rq * 4 + 2] + slot_p[dd * 16 + rq * 4 + 2]) * inv;
                float v3 = (ot[dd][rq * 4 + 3] + slot_p[dd * 16 + rq * 4 + 3]) * inv;
                i32x2 st;
                st[0] = cvt_pk_bf16(v0, v1);
                st[1] = cvt_pk_bf16(v2, v3);
                *(i32x2*)&ao[obase + dd * 32 + rq * 8 + hi * 4] = st;
            }
    }
}

extern "C" void kernel_launch(void* const* d_in, const int* in_sizes, int n_in,
                              void* d_out, int out_size, void* d_ws, size_t ws_size,
                              hipStream_t stream) {
    const float* x  = (const float*)d_in[0];
    const float* wq = (const float*)d_in[1];
    const float* bq = (const float*)d_in[2];
    const float* wk = (const float*)d_in[3];
    const float* bk = (const float*)d_in[4];
    const float* wv = (const float*)d_in[5];
    const float* bv = (const float*)d_in[6];
    const float* wo = (const float*)d_in[7];
    const float* bo = (const float*)d_in[8];
    const float* rb = (const float*)d_in[9];

    char* ws = (char*)d_ws;
    short* xb  = (short*)(ws);                 // 8 MB (reused as ao after projections)
    short* wqt = (short*)(ws + (8u  << 20));   // 2 MB each
    short* wkt = (short*)(ws + (10u << 20));
    short* wvt = (short*)(ws + (12u << 20));
    short* wot = (short*)(ws + (14u << 20));
    short* qb  = (short*)(ws + (16u << 20));   // 8 MB
    short* kb  = (short*)(ws + (24u << 20));   // 8 MB
    short* vb  = (short*)(ws + (32u << 20));   // 8 MB (dead after transpose_v)
    short* vt  = (short*)(ws + (40u << 20));   // 8 MB
    f32x4* bqt = (f32x4*)(ws + (32u << 20));   // 1 MB, built after transpose_v
    short* ao  = xb;

    cvt_x<<<4096, 256, 0, stream>>>(x, xb);
    transpose_w<<<256, 256, 0, stream>>>(wq, wqt);
    transpose_w<<<256, 256, 0, stream>>>(wk, wkt);
    transpose_w<<<256, 256, 0, stream>>>(wv, wvt);
    transpose_w<<<256, 256, 0, stream>>>(wo, wot);

    gemm_bias<0><<<512, 256, 0, stream>>>(xb, wqt, bq, qb);
    gemm_bias<1><<<512, 256, 0, stream>>>(xb, wkt, bk, kb);
    gemm_bias<1><<<512, 256, 0, stream>>>(xb, wvt, bv, vb);
    transpose_v<<<dim3(32, 32), 256, 0, stream>>>(vb, vt);
    build_biasq<<<256, 256, 0, stream>>>(rb, bqt);

    attn_kernel<<<512, 512, 0, stream>>>(qb, kb, vt, bqt, ao);

    gemm_bias<3><<<512, 256, 0, stream>>>(ao, wot, bo, d_out);
}

// Round 11
// 143.243 us; speedup vs baseline: 1.1185x; 1.1185x over previous
//
#include <hip/hip_runtime.h>
#include <hip/hip_bf16.h>

#define D_MODEL 1024
#define NHEADS  16
#define HEADD   64
#define SEQ     2048
#define PERIOD  4096
#define LOG2E   1.44269504088896340736f

typedef __attribute__((ext_vector_type(4)))  float f32x4;
typedef __attribute__((ext_vector_type(16))) float f32x16;
typedef __attribute__((ext_vector_type(4)))  float fvec4;
typedef __attribute__((ext_vector_type(8)))  short s16x8;
typedef __attribute__((ext_vector_type(4)))  short s16x4;
typedef __attribute__((ext_vector_type(2)))  int   i32x2;
typedef __attribute__((ext_vector_type(4)))  int   i32x4;

__device__ __forceinline__ short bf16_bits(float f) {
    union { float f; unsigned u; } v; v.f = f;
    unsigned r = v.u + 0x7FFFu + ((v.u >> 16) & 1u);   // RNE
    return (short)(r >> 16);
}

__device__ __forceinline__ int cvt_pk_bf16(float a, float b) {
    int r;
    asm("v_cvt_pk_bf16_f32 %0, %1, %2" : "=v"(r) : "v"(a), "v"(b));
    return r;
}

__device__ __forceinline__ float exp2_hw(float x) {
    float r;
    asm("v_exp_f32 %0, %1" : "=v"(r) : "v"(x));   // bare 2^x, no OCML range code
    return r;
}

__device__ __forceinline__ void gload_lds16(const void* g, void* l) {
    __builtin_amdgcn_global_load_lds(
        (const __attribute__((address_space(1))) void*)g,
        (__attribute__((address_space(3))) void*)l, 16, 0, 0);
}

// ---------------- prep: x f32 -> bf16 ----------------
__global__ void cvt_x(const float* __restrict__ x, short* __restrict__ xb) {
    int i = blockIdx.x * blockDim.x + threadIdx.x;
    fvec4 v = ((const fvec4*)x)[i];
    s16x4 o;
    o.x = bf16_bits(v.x); o.y = bf16_bits(v.y);
    o.z = bf16_bits(v.z); o.w = bf16_bits(v.w);
    ((s16x4*)xb)[i] = o;
}

// ---------------- prep: W [K][N] f32 -> Wt [N][K] bf16 ----------------
__global__ void transpose_w(const float* __restrict__ src, short* __restrict__ dst) {
    __shared__ float tile[64][65];
    int bx = blockIdx.x & 15, by = blockIdx.x >> 4;
    int n0 = bx * 64, k0 = by * 64;
    int t = threadIdx.x;
    int cr = t >> 4;
    int cc = (t & 15) * 4;
    for (int i = 0; i < 4; ++i) {
        int row = cr + i * 16;
        fvec4 v = *(const fvec4*)&src[(k0 + row) * D_MODEL + n0 + cc];
        tile[row][cc+0] = v.x; tile[row][cc+1] = v.y;
        tile[row][cc+2] = v.z; tile[row][cc+3] = v.w;
    }
    __syncthreads();
    for (int i = 0; i < 4; ++i) {
        int row = cr + i * 16;
        s16x4 o;
        o.x = bf16_bits(tile[cc+0][row]);
        o.y = bf16_bits(tile[cc+1][row]);
        o.z = bf16_bits(tile[cc+2][row]);
        o.w = bf16_bits(tile[cc+3][row]);
        *(s16x4*)&dst[(n0 + row) * D_MODEL + k0 + cc] = o;
    }
}

// ---------------- V [4096][1024] bf16 -> vt[(b*1024+h*64+d)][s] ----------------
__global__ void transpose_v(const short* __restrict__ vb, short* __restrict__ vt) {
    __shared__ short tile[64][80];
    int bh = blockIdx.y, st = blockIdx.x;
    int b = bh >> 4, h = bh & 15;
    int s0 = st * 64;
    int t = threadIdx.x;
    int row = t >> 3, ch = t & 7;
    for (int i = 0; i < 2; ++i) {
        int r = row + i * 32;
        *(s16x8*)&tile[r][ch * 8] =
            *(const s16x8*)&vb[(b * SEQ + s0 + r) * D_MODEL + h * HEADD + ch * 8];
    }
    __syncthreads();
    for (int i = 0; i < 2; ++i) {
        int d = row + i * 32;
        s16x8 o;
        #pragma unroll
        for (int j = 0; j < 8; ++j) o[j] = tile[ch * 8 + j][d];
        *(s16x8*)&vt[(b * D_MODEL + h * HEADD + d) * SEQ + s0 + ch * 8] = o;
    }
}

// ---------------- prep: phase-replicated bias table (log2 domain, minus fixed max) ----------------
// biasq[h*4096 + a] = {b[a..a+3]} * LOG2E - 16   (fixed-max softmax: m=16 folded in)
__global__ void build_biasq(const float* __restrict__ rb, f32x4* __restrict__ bq4) {
    int id = blockIdx.x * 256 + threadIdx.x;   // 0..65535 = h*4096 + a
    int h = id >> 12, a = id & 4095;
    f32x4 v;
    #pragma unroll
    for (int j = 0; j < 4; ++j)
        v[j] = rb[((a + j) & (PERIOD - 1)) * NHEADS + h] * LOG2E - 16.0f;
    bq4[id] = v;
}

// ---------------- fused QKV GEMM (r6-style __syncthreads loop) ----------------
// Bt = [3072][1024] (wqt|wkt|wvt contiguous). 128x64 tiles, BK=64, grid 1536 (3/CU).
__global__ __launch_bounds__(256, 3) void gemm_qkv(
    const short* __restrict__ A, const short* __restrict__ Bt,
    const float* __restrict__ biasq, const float* __restrict__ biask,
    const float* __restrict__ biasv,
    short* __restrict__ qb, short* __restrict__ kb, short* __restrict__ vb)
{
    __shared__ short As[2][128 * 64];   // 2 x 16 KB
    __shared__ short Bs[2][64 * 64];    // 2 x  8 KB
    int tid = threadIdx.x;
    int lane = tid & 63, wid = tid >> 6;
    int ln = lane & 15, g = lane >> 4;
    int wr = (wid >> 1) * 64, wc = (wid & 1) * 32;

    // XCD swizzle: 4 A-panels per XCD, 48 n-tiles each (bijective: 8*4*48 = 1536)
    int bid = blockIdx.x;
    int xcd = bid & 7, slot = bid >> 3;        // slot 0..191
    int mb = xcd * 4 + (slot / 48);            // 0..31
    int nb = slot % 48;                        // 0..47
    int m0 = mb * 128, n0 = nb * 64;

    int wsel = n0 >> 10;                       // 0:q 1:k 2:v
    const float* bias = wsel == 0 ? biasq : (wsel == 1 ? biask : biasv);
    short* dst = wsel == 0 ? qb : (wsel == 1 ? kb : vb);
    float osc = wsel == 0 ? (0.125f * LOG2E) : 1.0f;
    int ncol0 = n0 & 1023;

    f32x4 acc[4][2] = {};

    auto STAGE = [&](int kt, int bi) {
        #pragma unroll
        for (int i = 0; i < 4; ++i) {           // A: 128 rows x 8 chunks
            int idx = i * 256 + tid;
            int row = idx >> 3, ch = idx & 7;
            int gch = ch ^ (row & 7);
            gload_lds16(&A[(m0 + row) * 1024 + kt + gch * 8],
                        (char*)&As[bi][0] + (i * 256 + wid * 64) * 16);
        }
        #pragma unroll
        for (int i = 0; i < 2; ++i) {           // B: 64 rows x 8 chunks
            int idx = i * 256 + tid;
            int row = idx >> 3, ch = idx & 7;
            int gch = ch ^ (row & 7);
            gload_lds16(&Bt[(n0 + row) * 1024 + kt + gch * 8],
                        (char*)&Bs[bi][0] + (i * 256 + wid * 64) * 16);
        }
    };

    STAGE(0, 0);
    __syncthreads();

    for (int kt = 0; kt < 16; ++kt) {
        int bi = kt & 1;
        if (kt < 15) STAGE((kt + 1) * 64, bi ^ 1);   // prefetch next K-tile

        s16x8 af[4][2], bfr[2][2];
        #pragma unroll
        for (int m = 0; m < 4; ++m) {
            int row = wr + m * 16 + ln;
            #pragma unroll
            for (int kc = 0; kc < 2; ++kc)
                af[m][kc] = *(const s16x8*)&As[bi][row * 64 + (((kc * 4 + g) ^ (row & 7)) * 8)];
        }
        #pragma unroll
        for (int n = 0; n < 2; ++n) {
            int row = wc + n * 16 + ln;
            #pragma unroll
            for (int kc = 0; kc < 2; ++kc)
                bfr[n][kc] = *(const s16x8*)&Bs[bi][row * 64 + (((kc * 4 + g) ^ (row & 7)) * 8)];
        }
        #pragma unroll
        for (int kc = 0; kc < 2; ++kc)
            #pragma unroll
            for (int m = 0; m < 4; ++m)
                #pragma unroll
                for (int n = 0; n < 2; ++n)
                    acc[m][n] = __builtin_amdgcn_mfma_f32_16x16x32_bf16(af[m][kc], bfr[n][kc], acc[m][n], 0, 0, 0);

        __syncthreads();   // full fence: prefetch landed; all readers done
    }

    #pragma unroll
    for (int m = 0; m < 4; ++m) {
        int gr0 = m0 + wr + m * 16 + g * 4;
        #pragma unroll
        for (int n = 0; n < 2; ++n) {
            int gc = ncol0 + wc + n * 16 + ln;
            float bvv = bias[gc];
            #pragma unroll
            for (int r = 0; r < 4; ++r)
                dst[(gr0 + r) * 1024 + gc] = bf16_bits((acc[m][n][r] + bvv) * osc);
        }
    }
}

// ---------------- GEMM: C = A[M,1024]b @ Bt[n][k]b + bias (MODE 3: f32 out) ----------------
template<int MODE>
__global__ __launch_bounds__(256) void gemm_bias(
    const short* __restrict__ A, const short* __restrict__ Bt,
    const float* __restrict__ bias, void* __restrict__ Cout)
{
    __shared__ short As[2][128 * 64];   // 2 x 16 KB
    __shared__ short Bs[2][64 * 64];    // 2 x  8 KB
    int tid = threadIdx.x;
    int lane = tid & 63, wid = tid >> 6;
    int ln = lane & 15, g = lane >> 4;
    int wr = (wid >> 1) * 64, wc = (wid & 1) * 32;

    // XCD swizzle: same-M-panel blocks grouped per XCD (A panel L2-resident)
    int bid = blockIdx.x;                 // 0..511
    int xcd = bid & 7, slot = bid >> 3;   // slot 0..63
    int mb = xcd * 4 + (slot >> 4);       // 0..31
    int nb = slot & 15;                   // 0..15
    int m0 = mb * 128, n0 = nb * 64;

    f32x4 acc[4][2] = {};

    auto STAGE = [&](int kt, int bi) {
        #pragma unroll
        for (int i = 0; i < 4; ++i) {           // A: 128 rows x 8 chunks
            int idx = i * 256 + tid;
            int row = idx >> 3, ch = idx & 7;
            int gch = ch ^ (row & 7);
            gload_lds16(&A[(m0 + row) * 1024 + kt + gch * 8],
                        (char*)&As[bi][0] + (i * 256 + wid * 64) * 16);
        }
        #pragma unroll
        for (int i = 0; i < 2; ++i) {           // B: 64 rows x 8 chunks
            int idx = i * 256 + tid;
            int row = idx >> 3, ch = idx & 7;
            int gch = ch ^ (row & 7);
            gload_lds16(&Bt[(n0 + row) * 1024 + kt + gch * 8],
                        (char*)&Bs[bi][0] + (i * 256 + wid * 64) * 16);
        }
    };

    STAGE(0, 0);
    __syncthreads();

    for (int kt = 0; kt < 16; ++kt) {
        int bi = kt & 1;
        if (kt < 15) STAGE((kt + 1) * 64, bi ^ 1);   // prefetch next K-tile

        s16x8 af[4][2], bfr[2][2];
        #pragma unroll
        for (int m = 0; m < 4; ++m) {
            int row = wr + m * 16 + ln;
            #pragma unroll
            for (int kc = 0; kc < 2; ++kc)
                af[m][kc] = *(const s16x8*)&As[bi][row * 64 + (((kc * 4 + g) ^ (row & 7)) * 8)];
        }
        #pragma unroll
        for (int n = 0; n < 2; ++n) {
            int row = wc + n * 16 + ln;
            #pragma unroll
            for (int kc = 0; kc < 2; ++kc)
                bfr[n][kc] = *(const s16x8*)&Bs[bi][row * 64 + (((kc * 4 + g) ^ (row & 7)) * 8)];
        }
        #pragma unroll
        for (int kc = 0; kc < 2; ++kc)
            #pragma unroll
            for (int m = 0; m < 4; ++m)
                #pragma unroll
                for (int n = 0; n < 2; ++n)
                    acc[m][n] = __builtin_amdgcn_mfma_f32_16x16x32_bf16(af[m][kc], bfr[n][kc], acc[m][n], 0, 0, 0);

        __syncthreads();   // drains vmcnt(0): prefetch landed; all readers done
    }

    #pragma unroll
    for (int m = 0; m < 4; ++m) {
        int gr0 = m0 + wr + m * 16 + g * 4;
        #pragma unroll
        for (int n = 0; n < 2; ++n) {
            int gc = n0 + wc + n * 16 + ln;
            float bv = bias[gc];
            #pragma unroll
            for (int r = 0; r < 4; ++r) {
                int gr = gr0 + r;
                float v = acc[m][n][r] + bv;
                if (MODE == 0)      ((short*)Cout)[gr * 1024 + gc] = bf16_bits(v * (0.125f * LOG2E));
                else if (MODE == 1) ((short*)Cout)[gr * 1024 + gc] = bf16_bits(v);
                else                ((float*)Cout)[gr * 1024 + gc] = v;
            }
        }
    }
}

// ---------------- fused flash attention: split-KV 8-wave blocks, fixed-max softmax ----------------
// __launch_bounds__(512, 2): 2 blocks/CU (the LDS limit) -> 128-VGPR cap, no spills.
__global__ __launch_bounds__(512, 2) void attn_kernel(
    const short* __restrict__ qb,     // [4096][1024], pre-scaled by 0.125*log2e
    const short* __restrict__ kb,     // [4096][1024]
    const short* __restrict__ vt,     // [(b*1024+h*64+d)][2048]
    const f32x4* __restrict__ biasq,  // [16][4096], log2 domain, minus 16
    short* __restrict__ ao)           // [4096][1024]
{
    // [half][buf][0=K,1=V][64*64] shorts = 64 KB; merge area reuses this after the loop
    __shared__ short KV[2][2][2][64 * 64];

    int tid = threadIdx.x;
    int half = tid >> 8;               // 0: keys [0,1024)   1: keys [1024,2048)
    int tid_h = tid & 255;
    int lane = tid & 63;
    int wid_h = (tid >> 6) & 3;
    int l31 = lane & 31, hi = lane >> 5;

    // XCD swizzle: all 16 q-blocks of one (h,b) pinned to one XCD
    int bid = blockIdx.x;                 // 0..511
    int xcd = bid & 7, slot = bid >> 3;   // 0..63
    int hb = xcd * 4 + (slot >> 4);       // 0..31
    int qt = slot & 15;
    int h = hb & 15, b = hb >> 4;
    int q0 = qt * 128 + wid_h * 32;
    int qrow = q0 + l31;
    int kbase = half * 1024;

    // Q fragments (B-operand: col=q, k-contiguous)
    s16x8 aq[4];
    #pragma unroll
    for (int kk = 0; kk < 4; ++kk)
        aq[kk] = *(const s16x8*)&qb[(b * SEQ + qrow) * D_MODEL + h * HEADD + kk * 16 + hi * 8];

    const f32x4* bq = biasq + h * PERIOD;

    float lrow = 0.f;
    f32x16 ot[2] = {};

    auto STAGE = [&](int k0, int bi) {   // k0 absolute key index
        #pragma unroll
        for (int i = 0; i < 2; ++i) {
            int idx = i * 256 + tid_h;
            int row = idx >> 3, ch = idx & 7;
            int gch = ch ^ ((row & 7) ^ ((row >> 3) & 3));
            gload_lds16(&kb[(b * SEQ + k0 + row) * D_MODEL + h * HEADD + gch * 8],
                        (char*)&KV[half][bi][0][0] + (i * 256 + wid_h * 64) * 16);
            gload_lds16(&vt[(b * D_MODEL + h * HEADD + row) * SEQ + k0 + gch * 8],
                        (char*)&KV[half][bi][1][0] + (i * 256 + wid_h * 64) * 16);
        }
    };

    STAGE(kbase, 0);
    __syncthreads();

    for (int kt = 0; kt < 16; ++kt) {
        int k0 = kbase + kt * 64;
        int bi = kt & 1;
        if (kt < 15) STAGE(k0 + 64, bi ^ 1);   // prefetch next K/V tile

        // bias gathers issued early (overlap MFMA)
        f32x4 bv[2][4];
        #pragma unroll
        for (int kt32 = 0; kt32 < 2; ++kt32)
            #pragma unroll
            for (int rq = 0; rq < 4; ++rq) {
                int kq = k0 + kt32 * 32 + rq * 8 + hi * 4;
                bv[kt32][rq] = bq[(qrow - kq - 3) & (PERIOD - 1)];
            }

        // S^T = K · Q^T  (rows=k, cols=q), log2 domain
        f32x16 s[2];
        const short* Ksp = &KV[half][bi][0][0];
        const short* Vsp = &KV[half][bi][1][0];
        __builtin_amdgcn_s_setprio(1);
        #pragma unroll
        for (int kt32 = 0; kt32 < 2; ++kt32) {
            f32x16 acc = {};
            int rowK = kt32 * 32 + l31;
            int swz = (rowK & 7) ^ ((rowK >> 3) & 3);
            #pragma unroll
            for (int kk = 0; kk < 4; ++kk) {
                s16x8 kf = *(const s16x8*)&Ksp[rowK * 64 + (((2 * kk + hi) ^ swz) * 8)];
                acc = __builtin_amdgcn_mfma_f32_32x32x16_bf16(kf, aq[kk], acc, 0, 0, 0);
            }
            s[kt32] = acc;
        }
        __builtin_amdgcn_s_setprio(0);

        // p = exp2(score + bias - 16): fixed-max softmax, bare v_exp_f32
        #pragma unroll
        for (int kt32 = 0; kt32 < 2; ++kt32)
            #pragma unroll
            for (int rq = 0; rq < 4; ++rq) {
                s[kt32][rq * 4 + 0] = exp2_hw(s[kt32][rq * 4 + 0] + bv[kt32][rq][3]);
                s[kt32][rq * 4 + 1] = exp2_hw(s[kt32][rq * 4 + 1] + bv[kt32][rq][2]);
                s[kt32][rq * 4 + 2] = exp2_hw(s[kt32][rq * 4 + 2] + bv[kt32][rq][1]);
                s[kt32][rq * 4 + 3] = exp2_hw(s[kt32][rq * 4 + 3] + bv[kt32][rq][0]);
            }

        // l accumulation: tree over 32 in-lane values + cross-half partner add
        float sm[16];
        #pragma unroll
        for (int t = 0; t < 16; ++t) sm[t] = s[0][t] + s[1][t];
        #pragma unroll
        for (int t = 0; t < 8; ++t) sm[t] += sm[t + 8];
        #pragma unroll
        for (int t = 0; t < 4; ++t) sm[t] += sm[t + 4];
        float psum = (sm[0] + sm[1]) + (sm[2] + sm[3]);
        {
            i32x2 r = __builtin_amdgcn_permlane32_swap(__float_as_int(psum), __float_as_int(psum), false, false);
            psum = __int_as_float(r[0]) + __int_as_float(r[1]);
        }
        lrow += psum;

        // P repack (regs only, proven shfl_xor form) + PV: O^T += V^T . P
        #pragma unroll
        for (int kt32 = 0; kt32 < 2; ++kt32) {
            int pk[8];
            #pragma unroll
            for (int i = 0; i < 8; ++i)
                pk[i] = cvt_pk_bf16(s[kt32][2 * i], s[kt32][2 * i + 1]);
            #pragma unroll
            for (int ks = 0; ks < 2; ++ks) {
                int a0 = pk[ks * 4 + 0], b0 = pk[ks * 4 + 2];
                int a1 = pk[ks * 4 + 1], b1 = pk[ks * 4 + 3];
                int a0s = __shfl_xor(a0, 32), b0s = __shfl_xor(b0, 32);
                int a1s = __shfl_xor(a1, 32), b1s = __shfl_xor(b1, 32);
                i32x4 wi;
                wi[0] = (lane < 32) ? a0 : b0s;   // k = hi*8 + 0,1
                wi[1] = (lane < 32) ? a1 : b1s;   // k = hi*8 + 2,3
                wi[2] = (lane < 32) ? a0s : b0;   // k = hi*8 + 4,5
                wi[3] = (lane < 32) ? a1s : b1;   // k = hi*8 + 6,7
                s16x8 pb = __builtin_bit_cast(s16x8, wi);
                __builtin_amdgcn_s_setprio(1);
                #pragma unroll
                for (int dd = 0; dd < 2; ++dd) {
                    int rowV = dd * 32 + l31;
                    int swzV = (rowV & 7) ^ ((rowV >> 3) & 3);
                    int chV = kt32 * 4 + ks * 2 + hi;
                    s16x8 vf = *(const s16x8*)&Vsp[rowV * 64 + ((chV ^ swzV) * 8)];
                    ot[dd] = __builtin_amdgcn_mfma_f32_32x32x16_bf16(vf, pb, ot[dd], 0, 0, 0);
                }
                __builtin_amdgcn_s_setprio(0);
            }
        }

        __syncthreads();   // drains vmcnt(0): prefetch landed; all readers done
    }

    // ---- merge the two KV halves via LDS (K/V buffers are dead now) ----
    float* mbuf = (float*)&KV[0][0][0][0];
    float* slot_p = mbuf + (wid_h * 64 + lane) * 33;   // stride 33 -> conflict-free
    if (half == 1) {
        #pragma unroll
        for (int dd = 0; dd < 2; ++dd)
            #pragma unroll
            for (int t = 0; t < 16; ++t)
                slot_p[dd * 16 + t] = ot[dd][t];
        slot_p[32] = lrow;
    }
    __syncthreads();
    if (half == 0) {
        lrow += slot_p[32];
        float inv = 1.0f / lrow;
        int obase = (b * SEQ + qrow) * D_MODEL + h * HEADD;
        #pragma unroll
        for (int dd = 0; dd < 2; ++dd)
            #pragma unroll
            for (int rq = 0; rq < 4; ++rq) {
                float v0 = (ot[dd][rq * 4 + 0] + slot_p[dd * 16 + rq * 4 + 0]) * inv;
                float v1 = (ot[dd][rq * 4 + 1] + slot_p[dd * 16 + rq * 4 + 1]) * inv;
                float v2 = (ot[dd][rq * 4 + 2] + slot_p[dd * 16 + rq * 4 + 2]) * inv;
                float v3 = (ot[dd][rq * 4 + 3] + slot_p[dd * 16 + rq * 4 + 3]) * inv;
                i32x2 st;
                st[0] = cvt_pk_bf16(v0, v1);
                st[1] = cvt_pk_bf16(v2, v3);
                *(i32x2*)&ao[obase + dd * 32 + rq * 8 + hi * 4] = st;
            }
    }
}

extern "C" void kernel_launch(void* const* d_in, const int* in_sizes, int n_in,
                              void* d_out, int out_size, void* d_ws, size_t ws_size,
                              hipStream_t stream) {
    const float* x  = (const float*)d_in[0];
    const float* wq = (const float*)d_in[1];
    const float* bq = (const float*)d_in[2];
    const float* wk = (const float*)d_in[3];
    const float* bk = (const float*)d_in[4];
    const float* wv = (const float*)d_in[5];
    const float* bv = (const float*)d_in[6];
    const float* wo = (const float*)d_in[7];
    const float* bo = (const float*)d_in[8];
    const float* rb = (const float*)d_in[9];

    char* ws = (char*)d_ws;
    short* xb  = (short*)(ws);                 // 8 MB (reused as ao after projections)
    short* wqt = (short*)(ws + (8u  << 20));   // 2 MB each; wqt|wkt|wvt contiguous = Bt[3072][1024]
    short* wkt = (short*)(ws + (10u << 20));
    short* wvt = (short*)(ws + (12u << 20));
    short* wot = (short*)(ws + (14u << 20));
    short* qb  = (short*)(ws + (16u << 20));   // 8 MB
    short* kb  = (short*)(ws + (24u << 20));   // 8 MB
    short* vb  = (short*)(ws + (32u << 20));   // 8 MB (dead after transpose_v)
    short* vt  = (short*)(ws + (40u << 20));   // 8 MB
    f32x4* bqt = (f32x4*)(ws + (32u << 20));   // 1 MB, built after transpose_v
    short* ao  = xb;

    cvt_x<<<4096, 256, 0, stream>>>(x, xb);
    transpose_w<<<256, 256, 0, stream>>>(wq, wqt);
    transpose_w<<<256, 256, 0, stream>>>(wk, wkt);
    transpose_w<<<256, 256, 0, stream>>>(wv, wvt);
    transpose_w<<<256, 256, 0, stream>>>(wo, wot);

    gemm_qkv<<<1536, 256, 0, stream>>>(xb, wqt, bq, bk, bv, qb, kb, vb);
    transpose_v<<<dim3(32, 32), 256, 0, stream>>>(vb, vt);
    build_biasq<<<256, 256, 0, stream>>>(rb, bqt);

    attn_kernel<<<512, 512, 0, stream>>>(qb, kb, vt, bqt, ao);

    gemm_bias<3><<<512, 256, 0, stream>>>(ao, wot, bo, (float*)d_out);
}